// Round 1
// baseline (1835.071 us; speedup 1.0000x reference)
//
#include <hip/hip_runtime.h>
#include <math.h>

#define N_NODES 100000
#define N_EDGES 1600000
#define IN_DIM 64
#define HID 128
#define OUT_DIM 2
#define N_GRAPHS 64

// ---------------- degree / norm ----------------
__global__ void k_deg_init(int* __restrict__ deg) {
    int i = blockIdx.x * blockDim.x + threadIdx.x;
    if (i < N_NODES) deg[i] = 1;  // self loop
}

__global__ void k_deg_accum(const int* __restrict__ dst, int* __restrict__ deg) {
    int stride = gridDim.x * blockDim.x;
    for (int e = blockIdx.x * blockDim.x + threadIdx.x; e < N_EDGES; e += stride)
        atomicAdd(&deg[dst[e]], 1);
}

__global__ void k_dinv(const int* __restrict__ deg, float* __restrict__ dinv) {
    int i = blockIdx.x * blockDim.x + threadIdx.x;
    if (i < N_NODES) dinv[i] = rsqrtf((float)deg[i]);
}

// ---------------- dense transform: out[N,HID] = in[N,K] @ W[K,HID] ----------------
template <int K>
__global__ void k_gemm(const float* __restrict__ in, const float* __restrict__ W,
                       float* __restrict__ out) {
    __shared__ float xs[K];
    int row = blockIdx.x;
    int j = threadIdx.x;  // 0..127
    if (j < K) xs[j] = in[row * K + j];
    __syncthreads();
    float acc = 0.f;
#pragma unroll
    for (int k = 0; k < K; ++k) acc += xs[k] * W[k * HID + j];
    out[row * HID + j] = acc;
}

// ---------------- aggregation ----------------
// init accumulator with the self-loop term: agg = h * dinv^2
__global__ void k_self(const float* __restrict__ h, const float* __restrict__ dinv,
                       float* __restrict__ agg) {
    long long stride = (long long)gridDim.x * blockDim.x;
    for (long long idx = (long long)blockIdx.x * blockDim.x + threadIdx.x;
         idx < (long long)N_NODES * HID; idx += stride) {
        int node = (int)(idx >> 7);
        float d = dinv[node];
        agg[idx] = h[idx] * d * d;
    }
}

// scatter-add edges: one 128-lane group per edge
__global__ void k_edges(const int* __restrict__ src, const int* __restrict__ dst,
                        const float* __restrict__ dinv, const float* __restrict__ h,
                        float* __restrict__ agg) {
    int lane = threadIdx.x & (HID - 1);
    int egrp = blockIdx.x * (blockDim.x >> 7) + (threadIdx.x >> 7);
    int estride = gridDim.x * (blockDim.x >> 7);
    for (int e = egrp; e < N_EDGES; e += estride) {
        int s = src[e];
        int d = dst[e];
        float norm = dinv[s] * dinv[d];
        atomicAdd(&agg[(long long)d * HID + lane], h[(long long)s * HID + lane] * norm);
    }
}

__global__ void k_bias_relu(const float* __restrict__ agg, const float* __restrict__ b,
                            float* __restrict__ out) {
    long long stride = (long long)gridDim.x * blockDim.x;
    for (long long idx = (long long)blockIdx.x * blockDim.x + threadIdx.x;
         idx < (long long)N_NODES * HID; idx += stride) {
        float v = agg[idx] + b[idx & (HID - 1)];
        out[idx] = v > 0.f ? v : 0.f;
    }
}

// ---------------- pooling ----------------
#define POOL_CHUNK 256
__global__ void k_pool(const float* __restrict__ h, const int* __restrict__ batch,
                       float* __restrict__ pooled, float* __restrict__ cnt) {
    int n0 = blockIdx.x * POOL_CHUNK;
    int n1 = n0 + POOL_CHUNK;
    if (n1 > N_NODES) n1 = N_NODES;
    if (n0 >= N_NODES) return;
    int j = threadIdx.x;  // 0..127
    float acc = 0.f;
    int cur = batch[n0];
    int c_local = 0;
    for (int n = n0; n < n1; ++n) {
        int g = batch[n];
        if (g != cur) {
            atomicAdd(&pooled[cur * HID + j], acc);
            if (j == 0) atomicAdd(&cnt[cur], (float)c_local);
            acc = 0.f;
            c_local = 0;
            cur = g;
        }
        acc += h[(long long)n * HID + j];
        ++c_local;
    }
    atomicAdd(&pooled[cur * HID + j], acc);
    if (j == 0) atomicAdd(&cnt[cur], (float)c_local);
}

// ---------------- head: mean, fc, log_softmax ----------------
__global__ void k_head(const float* __restrict__ pooled, const float* __restrict__ cnt,
                       const float* __restrict__ Wfc, const float* __restrict__ bfc,
                       float* __restrict__ out) {
    int g = threadIdx.x;
    if (g >= N_GRAPHS) return;
    float inv = 1.0f / fmaxf(cnt[g], 1.0f);
    float l0 = bfc[0], l1 = bfc[1];
    for (int j = 0; j < HID; ++j) {
        float p = pooled[g * HID + j] * inv;
        l0 += p * Wfc[j * OUT_DIM + 0];
        l1 += p * Wfc[j * OUT_DIM + 1];
    }
    float m = fmaxf(l0, l1);
    float lse = m + logf(expf(l0 - m) + expf(l1 - m));
    out[g * OUT_DIM + 0] = l0 - lse;
    out[g * OUT_DIM + 1] = l1 - lse;
}

extern "C" void kernel_launch(void* const* d_in, const int* in_sizes, int n_in,
                              void* d_out, int out_size, void* d_ws, size_t ws_size,
                              hipStream_t stream) {
    const float* x   = (const float*)d_in[0];
    const float* W1  = (const float*)d_in[1];
    const float* b1  = (const float*)d_in[2];
    const float* W2  = (const float*)d_in[3];
    const float* b2  = (const float*)d_in[4];
    const float* Wfc = (const float*)d_in[5];
    const float* bfc = (const float*)d_in[6];
    const int* ei    = (const int*)d_in[7];   // [2, E]
    const int* batch = (const int*)d_in[8];
    const int* src = ei;
    const int* dst = ei + N_EDGES;
    float* out = (float*)d_out;

    // workspace layout
    float* bufA   = (float*)d_ws;                       // N*HID
    float* bufB   = bufA + (long long)N_NODES * HID;    // N*HID
    int*   deg    = (int*)(bufB + (long long)N_NODES * HID);  // N
    float* dinv   = (float*)(deg + N_NODES);            // N
    float* pooled = dinv + N_NODES;                     // G*HID
    float* cnt    = pooled + N_GRAPHS * HID;            // G

    const int nblk_nodes = (N_NODES + 255) / 256;

    // degree + norm
    k_deg_init<<<nblk_nodes, 256, 0, stream>>>(deg);
    k_deg_accum<<<1024, 256, 0, stream>>>(dst, deg);
    k_dinv<<<nblk_nodes, 256, 0, stream>>>(deg, dinv);

    // ----- layer 1 -----
    k_gemm<IN_DIM><<<N_NODES, HID, 0, stream>>>(x, W1, bufA);
    k_self<<<2048, 256, 0, stream>>>(bufA, dinv, bufB);
    k_edges<<<8192, 256, 0, stream>>>(src, dst, dinv, bufA, bufB);
    k_bias_relu<<<2048, 256, 0, stream>>>(bufB, b1, bufA);

    // ----- layer 2 -----
    k_gemm<HID><<<N_NODES, HID, 0, stream>>>(bufA, W2, bufB);
    k_self<<<2048, 256, 0, stream>>>(bufB, dinv, bufA);
    k_edges<<<8192, 256, 0, stream>>>(src, dst, dinv, bufB, bufA);
    k_bias_relu<<<2048, 256, 0, stream>>>(bufA, b2, bufB);

    // ----- pool + head -----
    hipMemsetAsync(pooled, 0, (N_GRAPHS * HID + N_GRAPHS) * sizeof(float), stream);
    k_pool<<<(N_NODES + POOL_CHUNK - 1) / POOL_CHUNK, HID, 0, stream>>>(bufB, batch, pooled, cnt);
    k_head<<<1, 64, 0, stream>>>(pooled, cnt, Wfc, bfc, out);
}

// Round 2
// 915.649 us; speedup vs baseline: 2.0041x; 2.0041x over previous
//
#include <hip/hip_runtime.h>
#include <math.h>

#define N_NODES 100000
#define N_EDGES 1600000
#define IN_DIM 64
#define HID 128
#define OUT_DIM 2
#define N_GRAPHS 64

// ---------------- degree / norm ----------------
__global__ void k_deg_init(int* __restrict__ deg) {
    int i = blockIdx.x * blockDim.x + threadIdx.x;
    if (i < N_NODES) deg[i] = 1;  // self loop
}

__global__ void k_deg_accum(const int* __restrict__ dst, int* __restrict__ deg) {
    int stride = gridDim.x * blockDim.x;
    for (int e = blockIdx.x * blockDim.x + threadIdx.x; e < N_EDGES; e += stride)
        atomicAdd(&deg[dst[e]], 1);
}

__global__ void k_dinv(const int* __restrict__ deg, float* __restrict__ dinv) {
    int i = blockIdx.x * blockDim.x + threadIdx.x;
    if (i < N_NODES) dinv[i] = rsqrtf((float)deg[i]);
}

// ---------------- CSR build ----------------
// single-block scan over edge-degrees (deg[i]-1), writes row_start + cursor
#define SCAN_T 1024
__global__ void k_scan(const int* __restrict__ deg, int* __restrict__ row_start,
                       int* __restrict__ cursor) {
    __shared__ int sums[SCAN_T];
    int t = threadIdx.x;
    const int chunk = (N_NODES + SCAN_T - 1) / SCAN_T;  // 98
    int lo = t * chunk;
    int hi = lo + chunk;
    if (hi > N_NODES) hi = N_NODES;
    int s = 0;
    for (int i = lo; i < hi; ++i) s += deg[i] - 1;
    sums[t] = s;
    __syncthreads();
    for (int off = 1; off < SCAN_T; off <<= 1) {
        int v = 0;
        if (t >= off) v = sums[t - off];
        __syncthreads();
        if (t >= off) sums[t] += v;
        __syncthreads();
    }
    int base = (t == 0) ? 0 : sums[t - 1];
    for (int i = lo; i < hi; ++i) {
        row_start[i] = base;
        cursor[i] = base;
        base += deg[i] - 1;
    }
    if (t == SCAN_T - 1) row_start[N_NODES] = base;
}

__global__ void k_scatter(const int* __restrict__ src, const int* __restrict__ dst,
                          int* __restrict__ cursor, int* __restrict__ csr) {
    int stride = gridDim.x * blockDim.x;
    for (int e = blockIdx.x * blockDim.x + threadIdx.x; e < N_EDGES; e += stride) {
        int d = dst[e];
        int p = atomicAdd(&cursor[d], 1);
        csr[p] = src[e];
    }
}

// ---------------- aggregation (gather, CSR) ----------------
// layer 1: out[d] = dinv[d] * ( sum_{s in N(d)} dinv[s]*x[s] + dinv[d]*x[d] ), 64-wide
__global__ __launch_bounds__(256) void k_agg1(const int* __restrict__ row_start,
                                              const int* __restrict__ csr,
                                              const float* __restrict__ x,
                                              const float* __restrict__ dinv,
                                              float* __restrict__ out) {
    int d = blockIdx.x * 4 + (threadIdx.x >> 6);  // wave per node
    int lane = threadIdx.x & 63;
    float dd = dinv[d];
    float acc = dd * x[(long long)d * IN_DIM + lane];  // self loop (dd^2 after final mul)
    int e = row_start[d];
    int eend = row_start[d + 1];
    for (; e < eend; ++e) {
        int s = csr[e];
        float ds = dinv[s];
        acc += ds * x[(long long)s * IN_DIM + lane];
    }
    out[(long long)d * IN_DIM + lane] = dd * acc;
}

// layer 2: hs already = h1 * dinv; out[d] = dinv[d] * ( sum hs[s] + hs[d] ), 128-wide (float2/lane)
__global__ __launch_bounds__(256) void k_agg2(const int* __restrict__ row_start,
                                              const int* __restrict__ csr,
                                              const float* __restrict__ hs,
                                              const float* __restrict__ dinv,
                                              float* __restrict__ out) {
    int d = blockIdx.x * 4 + (threadIdx.x >> 6);
    int lane = threadIdx.x & 63;
    const float2* h2p = (const float2*)hs;
    float2* o2p = (float2*)out;
    float dd = dinv[d];
    float2 v = h2p[(long long)d * 64 + lane];
    float2 acc;
    acc.x = v.x;
    acc.y = v.y;
    int e = row_start[d];
    int eend = row_start[d + 1];
    for (; e < eend; ++e) {
        int s = csr[e];
        float2 w = h2p[(long long)s * 64 + lane];
        acc.x += w.x;
        acc.y += w.y;
    }
    acc.x *= dd;
    acc.y *= dd;
    o2p[(long long)d * 64 + lane] = acc;
}

// ---------------- fused GEMM: out[N,HID] = relu(in[N,K] @ W + b) (* dinv) ----------------
// 8 rows per block, 256 threads, transposed LDS tile, 4 outputs/thread
template <int K, int SCALE>
__global__ __launch_bounds__(256) void k_gemm8(const float* __restrict__ in,
                                               const float* __restrict__ W,
                                               const float* __restrict__ bias,
                                               const float* __restrict__ dinv,
                                               float* __restrict__ out) {
    __shared__ float xT[K * 8];
    int row0 = blockIdx.x * 8;
    int tid = threadIdx.x;
    for (int i = tid; i < 8 * K; i += 256) {
        int r = i / K, k = i % K;
        xT[k * 8 + r] = in[(long long)(row0 + r) * K + k];
    }
    __syncthreads();
    int j = tid & 127;
    int rh = tid >> 7;  // 0..1 -> rows rh*4 .. rh*4+3
    float a0 = 0.f, a1 = 0.f, a2 = 0.f, a3 = 0.f;
#pragma unroll 8
    for (int k = 0; k < K; ++k) {
        float w = W[k * HID + j];
        float4 xv = *(const float4*)&xT[k * 8 + rh * 4];
        a0 += w * xv.x;
        a1 += w * xv.y;
        a2 += w * xv.z;
        a3 += w * xv.w;
    }
    float b = bias[j];
    float acc[4] = {a0, a1, a2, a3};
#pragma unroll
    for (int r = 0; r < 4; ++r) {
        int row = row0 + rh * 4 + r;
        float v = acc[r] + b;
        v = v > 0.f ? v : 0.f;
        if (SCALE) v *= dinv[row];
        out[(long long)row * HID + j] = v;
    }
}

// ---------------- pooling ----------------
#define POOL_CHUNK 256
__global__ void k_pool(const float* __restrict__ h, const int* __restrict__ batch,
                       float* __restrict__ pooled, float* __restrict__ cnt) {
    int n0 = blockIdx.x * POOL_CHUNK;
    int n1 = n0 + POOL_CHUNK;
    if (n1 > N_NODES) n1 = N_NODES;
    if (n0 >= N_NODES) return;
    int j = threadIdx.x;  // 0..127
    float acc = 0.f;
    int cur = batch[n0];
    int c_local = 0;
    for (int n = n0; n < n1; ++n) {
        int g = batch[n];
        if (g != cur) {
            atomicAdd(&pooled[cur * HID + j], acc);
            if (j == 0) atomicAdd(&cnt[cur], (float)c_local);
            acc = 0.f;
            c_local = 0;
            cur = g;
        }
        acc += h[(long long)n * HID + j];
        ++c_local;
    }
    atomicAdd(&pooled[cur * HID + j], acc);
    if (j == 0) atomicAdd(&cnt[cur], (float)c_local);
}

// ---------------- head ----------------
__global__ void k_head(const float* __restrict__ pooled, const float* __restrict__ cnt,
                       const float* __restrict__ Wfc, const float* __restrict__ bfc,
                       float* __restrict__ out) {
    int g = threadIdx.x;
    if (g >= N_GRAPHS) return;
    float inv = 1.0f / fmaxf(cnt[g], 1.0f);
    float l0 = bfc[0], l1 = bfc[1];
    for (int j = 0; j < HID; ++j) {
        float p = pooled[g * HID + j] * inv;
        l0 += p * Wfc[j * OUT_DIM + 0];
        l1 += p * Wfc[j * OUT_DIM + 1];
    }
    float m = fmaxf(l0, l1);
    float lse = m + logf(expf(l0 - m) + expf(l1 - m));
    out[g * OUT_DIM + 0] = l0 - lse;
    out[g * OUT_DIM + 1] = l1 - lse;
}

extern "C" void kernel_launch(void* const* d_in, const int* in_sizes, int n_in,
                              void* d_out, int out_size, void* d_ws, size_t ws_size,
                              hipStream_t stream) {
    const float* x   = (const float*)d_in[0];
    const float* W1  = (const float*)d_in[1];
    const float* b1  = (const float*)d_in[2];
    const float* W2  = (const float*)d_in[3];
    const float* b2  = (const float*)d_in[4];
    const float* Wfc = (const float*)d_in[5];
    const float* bfc = (const float*)d_in[6];
    const int* ei    = (const int*)d_in[7];   // [2, E]
    const int* batch = (const int*)d_in[8];
    const int* src = ei;
    const int* dst = ei + N_EDGES;
    float* out = (float*)d_out;

    // workspace layout
    float* A = (float*)d_ws;                       // N*128 floats: agg1 (N*64) then agg2 (N*128)
    float* B = A + (long long)N_NODES * HID;       // N*128 floats: hs then h2
    int* row_start = (int*)(B + (long long)N_NODES * HID);  // N+1
    int* cursor = row_start + (N_NODES + 1);       // N
    int* deg = cursor + N_NODES;                   // N
    float* dinv = (float*)(deg + N_NODES);         // N
    int* csr = (int*)(dinv + N_NODES);             // E
    float* pooled = (float*)(csr + N_EDGES);       // G*HID
    float* cnt = pooled + N_GRAPHS * HID;          // G

    const int nblk_nodes = (N_NODES + 255) / 256;

    // degree + norm + CSR
    k_deg_init<<<nblk_nodes, 256, 0, stream>>>(deg);
    k_deg_accum<<<1024, 256, 0, stream>>>(dst, deg);
    k_dinv<<<nblk_nodes, 256, 0, stream>>>(deg, dinv);
    k_scan<<<1, SCAN_T, 0, stream>>>(deg, row_start, cursor);
    k_scatter<<<1024, 256, 0, stream>>>(src, dst, cursor, csr);

    // ----- layer 1: aggregate(x) -> GEMM (+bias+relu, *dinv for next layer) -----
    k_agg1<<<N_NODES / 4, 256, 0, stream>>>(row_start, csr, x, dinv, A);
    k_gemm8<IN_DIM, 1><<<N_NODES / 8, 256, 0, stream>>>(A, W1, b1, dinv, B);  // B = hs = relu(.)*dinv

    // ----- layer 2: aggregate(hs) -> GEMM (+bias+relu) -----
    k_agg2<<<N_NODES / 4, 256, 0, stream>>>(row_start, csr, B, dinv, A);      // A = agg2 (N*128)
    k_gemm8<HID, 0><<<N_NODES / 8, 256, 0, stream>>>(A, W2, b2, dinv, B);     // B = h2

    // ----- pool + head -----
    hipMemsetAsync(pooled, 0, (N_GRAPHS * HID + N_GRAPHS) * sizeof(float), stream);
    k_pool<<<(N_NODES + POOL_CHUNK - 1) / POOL_CHUNK, HID, 0, stream>>>(B, batch, pooled, cnt);
    k_head<<<1, 64, 0, stream>>>(pooled, cnt, Wfc, bfc, out);
}

// Round 3
// 714.216 us; speedup vs baseline: 2.5693x; 1.2820x over previous
//
#include <hip/hip_runtime.h>
#include <math.h>

#define N_NODES 100000
#define N_EDGES 1600000
#define IN_DIM 64
#define HID 128
#define OUT_DIM 2
#define N_GRAPHS 64

#define SCAN_BLOCKS ((N_NODES + 255) / 256)  // 391

// ---------------- degree ----------------
// deg starts at 0 (memset); counts in-edges only. dinv computed later as rsqrt(deg+1).
__global__ void k_deg_accum(const int* __restrict__ dst, int* __restrict__ deg) {
    int stride = gridDim.x * blockDim.x;
    for (int e = blockIdx.x * blockDim.x + threadIdx.x; e < N_EDGES; e += stride)
        atomicAdd(&deg[dst[e]], 1);
}

// ---------------- CSR build: 3-phase scan ----------------
__global__ __launch_bounds__(256) void k_scan_part(const int* __restrict__ deg,
                                                   int* __restrict__ bsum) {
    __shared__ int red[256];
    int i = blockIdx.x * 256 + threadIdx.x;
    red[threadIdx.x] = (i < N_NODES) ? deg[i] : 0;
    __syncthreads();
    for (int off = 128; off > 0; off >>= 1) {
        if (threadIdx.x < off) red[threadIdx.x] += red[threadIdx.x + off];
        __syncthreads();
    }
    if (threadIdx.x == 0) bsum[blockIdx.x] = red[0];
}

__global__ __launch_bounds__(512) void k_scan_top(const int* __restrict__ bsum,
                                                  int* __restrict__ boff) {
    __shared__ int s[512];
    int t = threadIdx.x;
    s[t] = (t < SCAN_BLOCKS) ? bsum[t] : 0;
    __syncthreads();
    for (int off = 1; off < 512; off <<= 1) {
        int v = (t >= off) ? s[t - off] : 0;
        __syncthreads();
        s[t] += v;
        __syncthreads();
    }
    if (t < SCAN_BLOCKS) boff[t] = (t == 0) ? 0 : s[t - 1];
}

__global__ __launch_bounds__(256) void k_scan_write(const int* __restrict__ deg,
                                                    const int* __restrict__ boff,
                                                    int* __restrict__ row_start,
                                                    int* __restrict__ cursor,
                                                    float* __restrict__ dinv) {
    __shared__ int s[256];
    int t = threadIdx.x;
    int i = blockIdx.x * 256 + t;
    int v = (i < N_NODES) ? deg[i] : 0;
    s[t] = v;
    __syncthreads();
    for (int off = 1; off < 256; off <<= 1) {
        int u = (t >= off) ? s[t - off] : 0;
        __syncthreads();
        s[t] += u;
        __syncthreads();
    }
    if (i < N_NODES) {
        int base = boff[blockIdx.x];
        int excl = base + s[t] - v;
        row_start[i] = excl;
        cursor[i] = excl;
        dinv[i] = rsqrtf((float)(v + 1));  // +1 self loop
        if (i == N_NODES - 1) row_start[N_NODES] = base + s[t];
    }
}

__global__ void k_scatter(const int* __restrict__ src, const int* __restrict__ dst,
                          int* __restrict__ cursor, int* __restrict__ csr) {
    int stride = gridDim.x * blockDim.x;
    for (int e = blockIdx.x * blockDim.x + threadIdx.x; e < N_EDGES; e += stride) {
        int d = dst[e];
        int p = atomicAdd(&cursor[d], 1);
        csr[p] = src[e];
    }
}

// ---------------- aggregation (gather, CSR) ----------------
// layer 1: out[d] = dinv[d] * ( sum_{s in N(d)} dinv[s]*x[s] + dinv[d]*x[d] ), 64-wide
__global__ __launch_bounds__(256) void k_agg1(const int* __restrict__ row_start,
                                              const int* __restrict__ csr,
                                              const float* __restrict__ x,
                                              const float* __restrict__ dinv,
                                              float* __restrict__ out) {
    int d = blockIdx.x * 4 + (threadIdx.x >> 6);  // wave per node
    int lane = threadIdx.x & 63;
    float dd = dinv[d];
    float acc = dd * x[(long long)d * IN_DIM + lane];  // self loop (dd^2 after final mul)
    int e = row_start[d];
    int eend = row_start[d + 1];
    for (; e < eend; ++e) {
        int s = csr[e];
        float ds = dinv[s];
        acc += ds * x[(long long)s * IN_DIM + lane];
    }
    out[(long long)d * IN_DIM + lane] = dd * acc;
}

// layer 2: hs already = h1 * dinv; out[d] = dinv[d] * ( sum hs[s] + hs[d] ), 128-wide
__global__ __launch_bounds__(256) void k_agg2(const int* __restrict__ row_start,
                                              const int* __restrict__ csr,
                                              const float* __restrict__ hs,
                                              const float* __restrict__ dinv,
                                              float* __restrict__ out) {
    int d = blockIdx.x * 4 + (threadIdx.x >> 6);
    int lane = threadIdx.x & 63;
    const float2* h2p = (const float2*)hs;
    float2* o2p = (float2*)out;
    float dd = dinv[d];
    float2 v = h2p[(long long)d * 64 + lane];
    float2 acc;
    acc.x = v.x;
    acc.y = v.y;
    int e = row_start[d];
    int eend = row_start[d + 1];
    for (; e < eend; ++e) {
        int s = csr[e];
        float2 w = h2p[(long long)s * 64 + lane];
        acc.x += w.x;
        acc.y += w.y;
    }
    acc.x *= dd;
    acc.y *= dd;
    o2p[(long long)d * 64 + lane] = acc;
}

// ---------------- fused GEMM: out[N,HID] = relu(in[N,K] @ W + b) (* dinv) ----------------
template <int K, int SCALE>
__global__ __launch_bounds__(256) void k_gemm8(const float* __restrict__ in,
                                               const float* __restrict__ W,
                                               const float* __restrict__ bias,
                                               const float* __restrict__ dinv,
                                               float* __restrict__ out) {
    __shared__ float xT[K * 8];
    int row0 = blockIdx.x * 8;
    int tid = threadIdx.x;
    for (int i = tid; i < 8 * K; i += 256) {
        int r = i / K, k = i % K;
        xT[k * 8 + r] = in[(long long)(row0 + r) * K + k];
    }
    __syncthreads();
    int j = tid & 127;
    int rh = tid >> 7;  // 0..1 -> rows rh*4 .. rh*4+3
    float a0 = 0.f, a1 = 0.f, a2 = 0.f, a3 = 0.f;
#pragma unroll 8
    for (int k = 0; k < K; ++k) {
        float w = W[k * HID + j];
        float4 xv = *(const float4*)&xT[k * 8 + rh * 4];
        a0 += w * xv.x;
        a1 += w * xv.y;
        a2 += w * xv.z;
        a3 += w * xv.w;
    }
    float b = bias[j];
    float acc[4] = {a0, a1, a2, a3};
#pragma unroll
    for (int r = 0; r < 4; ++r) {
        int row = row0 + rh * 4 + r;
        float v = acc[r] + b;
        v = v > 0.f ? v : 0.f;
        if (SCALE) v *= dinv[row];
        out[(long long)row * HID + j] = v;
    }
}

// ---------------- pooling ----------------
#define POOL_CHUNK 256
__global__ void k_pool(const float* __restrict__ h, const int* __restrict__ batch,
                       float* __restrict__ pooled, float* __restrict__ cnt) {
    int n0 = blockIdx.x * POOL_CHUNK;
    int n1 = n0 + POOL_CHUNK;
    if (n1 > N_NODES) n1 = N_NODES;
    if (n0 >= N_NODES) return;
    int j = threadIdx.x;  // 0..127
    float acc = 0.f;
    int cur = batch[n0];
    int c_local = 0;
    for (int n = n0; n < n1; ++n) {
        int g = batch[n];
        if (g != cur) {
            atomicAdd(&pooled[cur * HID + j], acc);
            if (j == 0) atomicAdd(&cnt[cur], (float)c_local);
            acc = 0.f;
            c_local = 0;
            cur = g;
        }
        acc += h[(long long)n * HID + j];
        ++c_local;
    }
    atomicAdd(&pooled[cur * HID + j], acc);
    if (j == 0) atomicAdd(&cnt[cur], (float)c_local);
}

// ---------------- head ----------------
__global__ void k_head(const float* __restrict__ pooled, const float* __restrict__ cnt,
                       const float* __restrict__ Wfc, const float* __restrict__ bfc,
                       float* __restrict__ out) {
    int g = threadIdx.x;
    if (g >= N_GRAPHS) return;
    float inv = 1.0f / fmaxf(cnt[g], 1.0f);
    float l0 = bfc[0], l1 = bfc[1];
    for (int j = 0; j < HID; ++j) {
        float p = pooled[g * HID + j] * inv;
        l0 += p * Wfc[j * OUT_DIM + 0];
        l1 += p * Wfc[j * OUT_DIM + 1];
    }
    float m = fmaxf(l0, l1);
    float lse = m + logf(expf(l0 - m) + expf(l1 - m));
    out[g * OUT_DIM + 0] = l0 - lse;
    out[g * OUT_DIM + 1] = l1 - lse;
}

extern "C" void kernel_launch(void* const* d_in, const int* in_sizes, int n_in,
                              void* d_out, int out_size, void* d_ws, size_t ws_size,
                              hipStream_t stream) {
    const float* x   = (const float*)d_in[0];
    const float* W1  = (const float*)d_in[1];
    const float* b1  = (const float*)d_in[2];
    const float* W2  = (const float*)d_in[3];
    const float* b2  = (const float*)d_in[4];
    const float* Wfc = (const float*)d_in[5];
    const float* bfc = (const float*)d_in[6];
    const int* ei    = (const int*)d_in[7];   // [2, E]
    const int* batch = (const int*)d_in[8];
    const int* src = ei;
    const int* dst = ei + N_EDGES;
    float* out = (float*)d_out;

    // workspace layout
    float* A = (float*)d_ws;                       // N*128 floats
    float* B = A + (long long)N_NODES * HID;       // N*128 floats
    int* row_start = (int*)(B + (long long)N_NODES * HID);  // N+1
    int* cursor = row_start + (N_NODES + 1);       // N
    int* deg = cursor + N_NODES;                   // N
    float* dinv = (float*)(deg + N_NODES);         // N
    int* bsum = (int*)(dinv + N_NODES);            // SCAN_BLOCKS
    int* boff = bsum + SCAN_BLOCKS;                // SCAN_BLOCKS
    int* csr = boff + SCAN_BLOCKS;                 // E
    float* pooled = (float*)(csr + N_EDGES);       // G*HID
    float* cnt = pooled + N_GRAPHS * HID;          // G

    // degree + CSR
    hipMemsetAsync(deg, 0, N_NODES * sizeof(int), stream);
    k_deg_accum<<<1024, 256, 0, stream>>>(dst, deg);
    k_scan_part<<<SCAN_BLOCKS, 256, 0, stream>>>(deg, bsum);
    k_scan_top<<<1, 512, 0, stream>>>(bsum, boff);
    k_scan_write<<<SCAN_BLOCKS, 256, 0, stream>>>(deg, boff, row_start, cursor, dinv);
    k_scatter<<<1024, 256, 0, stream>>>(src, dst, cursor, csr);

    // ----- layer 1: aggregate(x) -> GEMM (+bias+relu, *dinv for next layer) -----
    k_agg1<<<N_NODES / 4, 256, 0, stream>>>(row_start, csr, x, dinv, A);
    k_gemm8<IN_DIM, 1><<<N_NODES / 8, 256, 0, stream>>>(A, W1, b1, dinv, B);  // B = hs

    // ----- layer 2: aggregate(hs) -> GEMM (+bias+relu) -----
    k_agg2<<<N_NODES / 4, 256, 0, stream>>>(row_start, csr, B, dinv, A);
    k_gemm8<HID, 0><<<N_NODES / 8, 256, 0, stream>>>(A, W2, b2, dinv, B);

    // ----- pool + head -----
    hipMemsetAsync(pooled, 0, (N_GRAPHS * HID + N_GRAPHS) * sizeof(float), stream);
    k_pool<<<(N_NODES + POOL_CHUNK - 1) / POOL_CHUNK, HID, 0, stream>>>(B, batch, pooled, cnt);
    k_head<<<1, 64, 0, stream>>>(pooled, cnt, Wfc, bfc, out);
}

// Round 4
// 699.611 us; speedup vs baseline: 2.6230x; 1.0209x over previous
//
#include <hip/hip_runtime.h>
#include <math.h>

#define N_NODES 100000
#define N_EDGES 1600000
#define IN_DIM 64
#define HID 128
#define OUT_DIM 2
#define N_GRAPHS 64

#define SCAN_BLOCKS ((N_NODES + 255) / 256)  // 391

typedef unsigned int uint32;
typedef unsigned short ushort16;

static __device__ __forceinline__ ushort f2bf(float f) {
    uint32 u = __float_as_uint(f);
    uint32 r = (u + 0x7fff + ((u >> 16) & 1)) >> 16;  // RNE
    return (ushort)r;
}
static __device__ __forceinline__ float bf2f(uint32 u) {
    return __uint_as_float(u << 16);
}

// ---------------- degree ----------------
__global__ void k_deg_accum(const int* __restrict__ dst, int* __restrict__ deg) {
    int stride = gridDim.x * blockDim.x;
    for (int e = blockIdx.x * blockDim.x + threadIdx.x; e < N_EDGES; e += stride)
        atomicAdd(&deg[dst[e]], 1);
}

// ---------------- CSR build: 3-phase scan ----------------
__global__ __launch_bounds__(256) void k_scan_part(const int* __restrict__ deg,
                                                   int* __restrict__ bsum) {
    __shared__ int red[256];
    int i = blockIdx.x * 256 + threadIdx.x;
    red[threadIdx.x] = (i < N_NODES) ? deg[i] : 0;
    __syncthreads();
    for (int off = 128; off > 0; off >>= 1) {
        if (threadIdx.x < off) red[threadIdx.x] += red[threadIdx.x + off];
        __syncthreads();
    }
    if (threadIdx.x == 0) bsum[blockIdx.x] = red[0];
}

__global__ __launch_bounds__(512) void k_scan_top(const int* __restrict__ bsum,
                                                  int* __restrict__ boff) {
    __shared__ int s[512];
    int t = threadIdx.x;
    s[t] = (t < SCAN_BLOCKS) ? bsum[t] : 0;
    __syncthreads();
    for (int off = 1; off < 512; off <<= 1) {
        int v = (t >= off) ? s[t - off] : 0;
        __syncthreads();
        s[t] += v;
        __syncthreads();
    }
    if (t < SCAN_BLOCKS) boff[t] = (t == 0) ? 0 : s[t - 1];
}

__global__ __launch_bounds__(256) void k_scan_write(const int* __restrict__ deg,
                                                    const int* __restrict__ boff,
                                                    int* __restrict__ row_start,
                                                    int* __restrict__ cursor,
                                                    float* __restrict__ dinv) {
    __shared__ int s[256];
    int t = threadIdx.x;
    int i = blockIdx.x * 256 + t;
    int v = (i < N_NODES) ? deg[i] : 0;
    s[t] = v;
    __syncthreads();
    for (int off = 1; off < 256; off <<= 1) {
        int u = (t >= off) ? s[t - off] : 0;
        __syncthreads();
        s[t] += u;
        __syncthreads();
    }
    if (i < N_NODES) {
        int base = boff[blockIdx.x];
        int excl = base + s[t] - v;
        row_start[i] = excl;
        cursor[i] = excl;
        dinv[i] = rsqrtf((float)(v + 1));  // +1 self loop
        if (i == N_NODES - 1) row_start[N_NODES] = base + s[t];
    }
}

__global__ void k_scatter(const int* __restrict__ src, const int* __restrict__ dst,
                          int* __restrict__ cursor, int* __restrict__ csr) {
    int stride = gridDim.x * blockDim.x;
    for (int e = blockIdx.x * blockDim.x + threadIdx.x; e < N_EDGES; e += stride) {
        int d = dst[e];
        int p = atomicAdd(&cursor[d], 1);
        csr[p] = src[e];
    }
}

// ---------------- pre-scale x by dinv -> bf16 ----------------
// xs[i,:] = bf16(dinv[i] * x[i,:]); idx over float4 groups (16 per node)
__global__ __launch_bounds__(256) void k_xscale(const float* __restrict__ x,
                                                const float* __restrict__ dinv,
                                                ushort* __restrict__ xs) {
    int idx = blockIdx.x * 256 + threadIdx.x;
    if (idx >= N_NODES * 16) return;
    float d = dinv[idx >> 4];
    float4 v = ((const float4*)x)[idx];
    ushort4 o;
    o.x = f2bf(v.x * d);
    o.y = f2bf(v.y * d);
    o.z = f2bf(v.z * d);
    o.w = f2bf(v.w * d);
    ((ushort4*)xs)[idx] = o;
}

// ---------------- aggregation (gather, CSR, bf16 rows) ----------------
// layer 1: out[d] = dinv[d] * ( sum_{s in N(d)} xs[s] + xs[d] ), xs already *dinv
__global__ __launch_bounds__(256) void k_agg1(const int* __restrict__ row_start,
                                              const int* __restrict__ csr,
                                              const ushort* __restrict__ xs,
                                              const float* __restrict__ dinv,
                                              float* __restrict__ out) {
    int d = blockIdx.x * 4 + (threadIdx.x >> 6);
    int lane = threadIdx.x & 63;
    float dd = dinv[d];
    float acc = bf2f(xs[(long long)d * IN_DIM + lane]);
    int e = row_start[d];
    int eend = row_start[d + 1];
    for (; e < eend; ++e) {
        int s = csr[e];
        acc += bf2f(xs[(long long)s * IN_DIM + lane]);
    }
    out[(long long)d * IN_DIM + lane] = dd * acc;
}

// layer 2: hs = bf16(h1*dinv), packed 2/uint; out[d] = dinv[d]*(sum hs[s] + hs[d]) f32
__global__ __launch_bounds__(256) void k_agg2(const int* __restrict__ row_start,
                                              const int* __restrict__ csr,
                                              const uint32* __restrict__ hs2,
                                              const float* __restrict__ dinv,
                                              float* __restrict__ out) {
    int d = blockIdx.x * 4 + (threadIdx.x >> 6);
    int lane = threadIdx.x & 63;
    float dd = dinv[d];
    uint32 u = hs2[(long long)d * 64 + lane];
    float a0 = bf2f(u & 0xffffu);
    float a1 = bf2f(u >> 16);
    int e = row_start[d];
    int eend = row_start[d + 1];
    for (; e < eend; ++e) {
        int s = csr[e];
        uint32 w = hs2[(long long)s * 64 + lane];
        a0 += bf2f(w & 0xffffu);
        a1 += bf2f(w >> 16);
    }
    float2 o;
    o.x = a0 * dd;
    o.y = a1 * dd;
    ((float2*)out)[(long long)d * 64 + lane] = o;
}

// ---------------- fused GEMM: out[N,HID] = relu(in[N,K] @ W + b) ----------------
// OUT_BF=1: write bf16(v*dinv[row]); OUT_BF=0: write f32 v
template <int K, int OUT_BF>
__global__ __launch_bounds__(256) void k_gemm8(const float* __restrict__ in,
                                               const float* __restrict__ W,
                                               const float* __restrict__ bias,
                                               const float* __restrict__ dinv,
                                               void* __restrict__ outv) {
    __shared__ float xT[K * 8];
    int row0 = blockIdx.x * 8;
    int tid = threadIdx.x;
    for (int i = tid; i < 8 * K; i += 256) {
        int r = i / K, k = i % K;
        xT[k * 8 + r] = in[(long long)(row0 + r) * K + k];
    }
    __syncthreads();
    int j = tid & 127;
    int rh = tid >> 7;
    float a0 = 0.f, a1 = 0.f, a2 = 0.f, a3 = 0.f;
#pragma unroll 8
    for (int k = 0; k < K; ++k) {
        float w = W[k * HID + j];
        float4 xv = *(const float4*)&xT[k * 8 + rh * 4];
        a0 += w * xv.x;
        a1 += w * xv.y;
        a2 += w * xv.z;
        a3 += w * xv.w;
    }
    float b = bias[j];
    float acc[4] = {a0, a1, a2, a3};
#pragma unroll
    for (int r = 0; r < 4; ++r) {
        int row = row0 + rh * 4 + r;
        float v = acc[r] + b;
        v = v > 0.f ? v : 0.f;
        if (OUT_BF) {
            ((ushort*)outv)[(long long)row * HID + j] = f2bf(v * dinv[row]);
        } else {
            ((float*)outv)[(long long)row * HID + j] = v;
        }
    }
}

// ---------------- pooling ----------------
#define POOL_CHUNK 256
__global__ void k_pool(const float* __restrict__ h, const int* __restrict__ batch,
                       float* __restrict__ pooled, float* __restrict__ cnt) {
    int n0 = blockIdx.x * POOL_CHUNK;
    int n1 = n0 + POOL_CHUNK;
    if (n1 > N_NODES) n1 = N_NODES;
    if (n0 >= N_NODES) return;
    int j = threadIdx.x;  // 0..127
    float acc = 0.f;
    int cur = batch[n0];
    int c_local = 0;
    for (int n = n0; n < n1; ++n) {
        int g = batch[n];
        if (g != cur) {
            atomicAdd(&pooled[cur * HID + j], acc);
            if (j == 0) atomicAdd(&cnt[cur], (float)c_local);
            acc = 0.f;
            c_local = 0;
            cur = g;
        }
        acc += h[(long long)n * HID + j];
        ++c_local;
    }
    atomicAdd(&pooled[cur * HID + j], acc);
    if (j == 0) atomicAdd(&cnt[cur], (float)c_local);
}

// ---------------- head ----------------
__global__ void k_head(const float* __restrict__ pooled, const float* __restrict__ cnt,
                       const float* __restrict__ Wfc, const float* __restrict__ bfc,
                       float* __restrict__ out) {
    int g = threadIdx.x;
    if (g >= N_GRAPHS) return;
    float inv = 1.0f / fmaxf(cnt[g], 1.0f);
    float l0 = bfc[0], l1 = bfc[1];
    for (int j = 0; j < HID; ++j) {
        float p = pooled[g * HID + j] * inv;
        l0 += p * Wfc[j * OUT_DIM + 0];
        l1 += p * Wfc[j * OUT_DIM + 1];
    }
    float m = fmaxf(l0, l1);
    float lse = m + logf(expf(l0 - m) + expf(l1 - m));
    out[g * OUT_DIM + 0] = l0 - lse;
    out[g * OUT_DIM + 1] = l1 - lse;
}

extern "C" void kernel_launch(void* const* d_in, const int* in_sizes, int n_in,
                              void* d_out, int out_size, void* d_ws, size_t ws_size,
                              hipStream_t stream) {
    const float* x   = (const float*)d_in[0];
    const float* W1  = (const float*)d_in[1];
    const float* b1  = (const float*)d_in[2];
    const float* W2  = (const float*)d_in[3];
    const float* b2  = (const float*)d_in[4];
    const float* Wfc = (const float*)d_in[5];
    const float* bfc = (const float*)d_in[6];
    const int* ei    = (const int*)d_in[7];   // [2, E]
    const int* batch = (const int*)d_in[8];
    const int* src = ei;
    const int* dst = ei + N_EDGES;
    float* out = (float*)d_out;

    // workspace layout
    float* bufA = (float*)d_ws;                    // N*128 f32: agg1 out (N*64), then agg2 out (N*128)
    float* bufB = bufA + (long long)N_NODES * HID; // N*128 f32: gemm2 out; start doubles as xs/hs bf16
    ushort* xs = (ushort*)bufB;                    // N*64 bf16 (dead before gemm2 writes bufB)
    ushort* hs = (ushort*)bufB;                    // N*128 bf16 (dead before gemm2 writes bufB)
    int* row_start = (int*)(bufB + (long long)N_NODES * HID);  // N+1
    int* cursor = row_start + (N_NODES + 1);       // N
    int* deg = cursor + N_NODES;                   // N
    float* dinv = (float*)(deg + N_NODES);         // N
    int* bsum = (int*)(dinv + N_NODES);            // SCAN_BLOCKS
    int* boff = bsum + SCAN_BLOCKS;                // SCAN_BLOCKS
    int* csr = boff + SCAN_BLOCKS;                 // E
    float* pooled = (float*)(csr + N_EDGES);       // G*HID
    float* cnt = pooled + N_GRAPHS * HID;          // G

    // degree + CSR
    hipMemsetAsync(deg, 0, N_NODES * sizeof(int), stream);
    k_deg_accum<<<1024, 256, 0, stream>>>(dst, deg);
    k_scan_part<<<SCAN_BLOCKS, 256, 0, stream>>>(deg, bsum);
    k_scan_top<<<1, 512, 0, stream>>>(bsum, boff);
    k_scan_write<<<SCAN_BLOCKS, 256, 0, stream>>>(deg, boff, row_start, cursor, dinv);
    k_scatter<<<1024, 256, 0, stream>>>(src, dst, cursor, csr);

    // ----- layer 1: xs = bf16(dinv*x); aggregate -> GEMM (writes hs = bf16(relu*dinv)) -----
    k_xscale<<<(N_NODES * 16 + 255) / 256, 256, 0, stream>>>(x, dinv, xs);
    k_agg1<<<N_NODES / 4, 256, 0, stream>>>(row_start, csr, xs, dinv, bufA);
    k_gemm8<IN_DIM, 1><<<N_NODES / 8, 256, 0, stream>>>(bufA, W1, b1, dinv, hs);

    // ----- layer 2: aggregate(hs) -> GEMM (f32 out) -----
    k_agg2<<<N_NODES / 4, 256, 0, stream>>>(row_start, csr, (const uint32*)hs, dinv, bufA);
    k_gemm8<HID, 0><<<N_NODES / 8, 256, 0, stream>>>(bufA, W2, b2, dinv, bufB);

    // ----- pool + head -----
    hipMemsetAsync(pooled, 0, (N_GRAPHS * HID + N_GRAPHS) * sizeof(float), stream);
    k_pool<<<(N_NODES + POOL_CHUNK - 1) / POOL_CHUNK, HID, 0, stream>>>(bufB, batch, pooled, cnt);
    k_head<<<1, 64, 0, stream>>>(pooled, cnt, Wfc, bfc, out);
}

// Round 5
// 507.590 us; speedup vs baseline: 3.6153x; 1.3783x over previous
//
#include <hip/hip_runtime.h>
#include <math.h>

#define N_NODES 100000
#define N_EDGES 1600000
#define IN_DIM 64
#define HID 128
#define OUT_DIM 2
#define N_GRAPHS 64

#define SCAN_BLOCKS ((N_NODES + 255) / 256)  // 391

typedef unsigned int uint32;

static __device__ __forceinline__ ushort f2bf(float f) {
    uint32 u = __float_as_uint(f);
    uint32 r = (u + 0x7fff + ((u >> 16) & 1)) >> 16;  // RNE
    return (ushort)r;
}
static __device__ __forceinline__ float bf2f(uint32 u) {
    return __uint_as_float(u << 16);
}
static __device__ __forceinline__ float bflo(uint32 u) { return bf2f(u & 0xffffu); }
static __device__ __forceinline__ float bfhi(uint32 u) { return bf2f(u >> 16); }

// ---------------- degree ----------------
__global__ void k_deg_accum(const int* __restrict__ dst, int* __restrict__ deg) {
    int stride = gridDim.x * blockDim.x;
    for (int e = blockIdx.x * blockDim.x + threadIdx.x; e < N_EDGES; e += stride)
        atomicAdd(&deg[dst[e]], 1);
}

// ---------------- CSR build: 3-phase scan ----------------
__global__ __launch_bounds__(256) void k_scan_part(const int* __restrict__ deg,
                                                   int* __restrict__ bsum) {
    __shared__ int red[256];
    int i = blockIdx.x * 256 + threadIdx.x;
    red[threadIdx.x] = (i < N_NODES) ? deg[i] : 0;
    __syncthreads();
    for (int off = 128; off > 0; off >>= 1) {
        if (threadIdx.x < off) red[threadIdx.x] += red[threadIdx.x + off];
        __syncthreads();
    }
    if (threadIdx.x == 0) bsum[blockIdx.x] = red[0];
}

__global__ __launch_bounds__(512) void k_scan_top(const int* __restrict__ bsum,
                                                  int* __restrict__ boff) {
    __shared__ int s[512];
    int t = threadIdx.x;
    s[t] = (t < SCAN_BLOCKS) ? bsum[t] : 0;
    __syncthreads();
    for (int off = 1; off < 512; off <<= 1) {
        int v = (t >= off) ? s[t - off] : 0;
        __syncthreads();
        s[t] += v;
        __syncthreads();
    }
    if (t < SCAN_BLOCKS) boff[t] = (t == 0) ? 0 : s[t - 1];
}

__global__ __launch_bounds__(256) void k_scan_write(const int* __restrict__ deg,
                                                    const int* __restrict__ boff,
                                                    int* __restrict__ row_start,
                                                    int* __restrict__ cursor,
                                                    float* __restrict__ dinv) {
    __shared__ int s[256];
    int t = threadIdx.x;
    int i = blockIdx.x * 256 + t;
    int v = (i < N_NODES) ? deg[i] : 0;
    s[t] = v;
    __syncthreads();
    for (int off = 1; off < 256; off <<= 1) {
        int u = (t >= off) ? s[t - off] : 0;
        __syncthreads();
        s[t] += u;
        __syncthreads();
    }
    if (i < N_NODES) {
        int base = boff[blockIdx.x];
        int excl = base + s[t] - v;
        row_start[i] = excl;
        cursor[i] = excl;
        dinv[i] = rsqrtf((float)(v + 1));  // +1 self loop
        if (i == N_NODES - 1) row_start[N_NODES] = base + s[t];
    }
}

__global__ void k_scatter(const int* __restrict__ src, const int* __restrict__ dst,
                          int* __restrict__ cursor, int* __restrict__ csr) {
    int stride = gridDim.x * blockDim.x;
    for (int e = blockIdx.x * blockDim.x + threadIdx.x; e < N_EDGES; e += stride) {
        int d = dst[e];
        int p = atomicAdd(&cursor[d], 1);
        csr[p] = src[e];
    }
}

// ---------------- pre-scale x by dinv -> bf16 ----------------
__global__ __launch_bounds__(256) void k_xscale(const float* __restrict__ x,
                                                const float* __restrict__ dinv,
                                                ushort* __restrict__ xs) {
    int idx = blockIdx.x * 256 + threadIdx.x;
    if (idx >= N_NODES * 16) return;
    float d = dinv[idx >> 4];
    float4 v = ((const float4*)x)[idx];
    ushort4 o;
    o.x = f2bf(v.x * d);
    o.y = f2bf(v.y * d);
    o.z = f2bf(v.z * d);
    o.w = f2bf(v.w * d);
    ((ushort4*)xs)[idx] = o;
}

// ---------------- aggregation (gather, CSR, bf16 rows, MLP-unrolled) ----------------
// layer 1: 2 nodes per wave (32 lanes/node), 1 uint32 (2 bf16) per lane, edge loop x4
__global__ __launch_bounds__(256) void k_agg1(const int* __restrict__ row_start,
                                              const int* __restrict__ csr,
                                              const uint32* __restrict__ xs,
                                              const float* __restrict__ dinv,
                                              float* __restrict__ out) {
    int d = blockIdx.x * 8 + (threadIdx.x >> 5);
    int l = threadIdx.x & 31;
    float dd = dinv[d];
    uint32 u = xs[(long long)d * 32 + l];
    float a0 = bflo(u), a1 = bfhi(u);
    int e = row_start[d];
    int eend = row_start[d + 1];
    for (; e + 3 < eend; e += 4) {
        int s0 = csr[e], s1 = csr[e + 1], s2 = csr[e + 2], s3 = csr[e + 3];
        uint32 w0 = xs[(long long)s0 * 32 + l];
        uint32 w1 = xs[(long long)s1 * 32 + l];
        uint32 w2 = xs[(long long)s2 * 32 + l];
        uint32 w3 = xs[(long long)s3 * 32 + l];
        a0 += bflo(w0) + bflo(w1) + bflo(w2) + bflo(w3);
        a1 += bfhi(w0) + bfhi(w1) + bfhi(w2) + bfhi(w3);
    }
    for (; e < eend; ++e) {
        uint32 w = xs[(long long)csr[e] * 32 + l];
        a0 += bflo(w);
        a1 += bfhi(w);
    }
    float2 o;
    o.x = a0 * dd;
    o.y = a1 * dd;
    ((float2*)out)[(long long)d * 32 + l] = o;
}

// layer 2: 2 nodes per wave (32 lanes/node), uint2 (4 bf16) per lane, edge loop x4
__global__ __launch_bounds__(256) void k_agg2(const int* __restrict__ row_start,
                                              const int* __restrict__ csr,
                                              const uint2* __restrict__ hs,
                                              const float* __restrict__ dinv,
                                              float* __restrict__ out) {
    int d = blockIdx.x * 8 + (threadIdx.x >> 5);
    int l = threadIdx.x & 31;
    float dd = dinv[d];
    uint2 u = hs[(long long)d * 32 + l];
    float a0 = bflo(u.x), a1 = bfhi(u.x), a2 = bflo(u.y), a3 = bfhi(u.y);
    int e = row_start[d];
    int eend = row_start[d + 1];
    for (; e + 3 < eend; e += 4) {
        int s0 = csr[e], s1 = csr[e + 1], s2 = csr[e + 2], s3 = csr[e + 3];
        uint2 w0 = hs[(long long)s0 * 32 + l];
        uint2 w1 = hs[(long long)s1 * 32 + l];
        uint2 w2 = hs[(long long)s2 * 32 + l];
        uint2 w3 = hs[(long long)s3 * 32 + l];
        a0 += bflo(w0.x) + bflo(w1.x) + bflo(w2.x) + bflo(w3.x);
        a1 += bfhi(w0.x) + bfhi(w1.x) + bfhi(w2.x) + bfhi(w3.x);
        a2 += bflo(w0.y) + bflo(w1.y) + bflo(w2.y) + bflo(w3.y);
        a3 += bfhi(w0.y) + bfhi(w1.y) + bfhi(w2.y) + bfhi(w3.y);
    }
    for (; e < eend; ++e) {
        uint2 w = hs[(long long)csr[e] * 32 + l];
        a0 += bflo(w.x);
        a1 += bfhi(w.x);
        a2 += bflo(w.y);
        a3 += bfhi(w.y);
    }
    float4 o;
    o.x = a0 * dd;
    o.y = a1 * dd;
    o.z = a2 * dd;
    o.w = a3 * dd;
    ((float4*)out)[(long long)d * 32 + l] = o;
}

// ---------------- fused GEMM: out[N,HID] = relu(in[N,K] @ W + b) ----------------
template <int K, int OUT_BF>
__global__ __launch_bounds__(256) void k_gemm8(const float* __restrict__ in,
                                               const float* __restrict__ W,
                                               const float* __restrict__ bias,
                                               const float* __restrict__ dinv,
                                               void* __restrict__ outv) {
    __shared__ float xT[K * 8];
    int row0 = blockIdx.x * 8;
    int tid = threadIdx.x;
    for (int i = tid; i < 8 * K; i += 256) {
        int r = i / K, k = i % K;
        xT[k * 8 + r] = in[(long long)(row0 + r) * K + k];
    }
    __syncthreads();
    int j = tid & 127;
    int rh = tid >> 7;
    float a0 = 0.f, a1 = 0.f, a2 = 0.f, a3 = 0.f;
#pragma unroll 8
    for (int k = 0; k < K; ++k) {
        float w = W[k * HID + j];
        float4 xv = *(const float4*)&xT[k * 8 + rh * 4];
        a0 += w * xv.x;
        a1 += w * xv.y;
        a2 += w * xv.z;
        a3 += w * xv.w;
    }
    float b = bias[j];
    float acc[4] = {a0, a1, a2, a3};
#pragma unroll
    for (int r = 0; r < 4; ++r) {
        int row = row0 + rh * 4 + r;
        float v = acc[r] + b;
        v = v > 0.f ? v : 0.f;
        if (OUT_BF) {
            ((ushort*)outv)[(long long)row * HID + j] = f2bf(v * dinv[row]);
        } else {
            ((float*)outv)[(long long)row * HID + j] = v;
        }
    }
}

// ---------------- pooling ----------------
#define POOL_CHUNK 256
__global__ void k_pool(const float* __restrict__ h, const int* __restrict__ batch,
                       float* __restrict__ pooled, float* __restrict__ cnt) {
    int n0 = blockIdx.x * POOL_CHUNK;
    int n1 = n0 + POOL_CHUNK;
    if (n1 > N_NODES) n1 = N_NODES;
    if (n0 >= N_NODES) return;
    int j = threadIdx.x;  // 0..127
    float acc = 0.f;
    int cur = batch[n0];
    int c_local = 0;
    for (int n = n0; n < n1; ++n) {
        int g = batch[n];
        if (g != cur) {
            atomicAdd(&pooled[cur * HID + j], acc);
            if (j == 0) atomicAdd(&cnt[cur], (float)c_local);
            acc = 0.f;
            c_local = 0;
            cur = g;
        }
        acc += h[(long long)n * HID + j];
        ++c_local;
    }
    atomicAdd(&pooled[cur * HID + j], acc);
    if (j == 0) atomicAdd(&cnt[cur], (float)c_local);
}

// ---------------- head ----------------
__global__ void k_head(const float* __restrict__ pooled, const float* __restrict__ cnt,
                       const float* __restrict__ Wfc, const float* __restrict__ bfc,
                       float* __restrict__ out) {
    int g = threadIdx.x;
    if (g >= N_GRAPHS) return;
    float inv = 1.0f / fmaxf(cnt[g], 1.0f);
    float l0 = bfc[0], l1 = bfc[1];
    for (int j = 0; j < HID; ++j) {
        float p = pooled[g * HID + j] * inv;
        l0 += p * Wfc[j * OUT_DIM + 0];
        l1 += p * Wfc[j * OUT_DIM + 1];
    }
    float m = fmaxf(l0, l1);
    float lse = m + logf(expf(l0 - m) + expf(l1 - m));
    out[g * OUT_DIM + 0] = l0 - lse;
    out[g * OUT_DIM + 1] = l1 - lse;
}

extern "C" void kernel_launch(void* const* d_in, const int* in_sizes, int n_in,
                              void* d_out, int out_size, void* d_ws, size_t ws_size,
                              hipStream_t stream) {
    const float* x   = (const float*)d_in[0];
    const float* W1  = (const float*)d_in[1];
    const float* b1  = (const float*)d_in[2];
    const float* W2  = (const float*)d_in[3];
    const float* b2  = (const float*)d_in[4];
    const float* Wfc = (const float*)d_in[5];
    const float* bfc = (const float*)d_in[6];
    const int* ei    = (const int*)d_in[7];   // [2, E]
    const int* batch = (const int*)d_in[8];
    const int* src = ei;
    const int* dst = ei + N_EDGES;
    float* out = (float*)d_out;

    // workspace layout
    float* bufA = (float*)d_ws;                    // N*128 f32
    float* bufB = bufA + (long long)N_NODES * HID; // N*128 f32; start doubles as xs/hs bf16
    ushort* xs = (ushort*)bufB;                    // N*64 bf16
    ushort* hs = (ushort*)bufB;                    // N*128 bf16
    int* row_start = (int*)(bufB + (long long)N_NODES * HID);  // N+1
    int* cursor = row_start + (N_NODES + 1);       // N
    int* deg = cursor + N_NODES;                   // N
    float* dinv = (float*)(deg + N_NODES);         // N
    int* bsum = (int*)(dinv + N_NODES);            // SCAN_BLOCKS
    int* boff = bsum + SCAN_BLOCKS;                // SCAN_BLOCKS
    int* csr = boff + SCAN_BLOCKS;                 // E
    float* pooled = (float*)(csr + N_EDGES);       // G*HID
    float* cnt = pooled + N_GRAPHS * HID;          // G

    // degree + CSR
    hipMemsetAsync(deg, 0, N_NODES * sizeof(int), stream);
    k_deg_accum<<<1024, 256, 0, stream>>>(dst, deg);
    k_scan_part<<<SCAN_BLOCKS, 256, 0, stream>>>(deg, bsum);
    k_scan_top<<<1, 512, 0, stream>>>(bsum, boff);
    k_scan_write<<<SCAN_BLOCKS, 256, 0, stream>>>(deg, boff, row_start, cursor, dinv);
    k_scatter<<<1024, 256, 0, stream>>>(src, dst, cursor, csr);

    // ----- layer 1: xs = bf16(dinv*x); aggregate -> GEMM (writes hs = bf16(relu*dinv)) -----
    k_xscale<<<(N_NODES * 16 + 255) / 256, 256, 0, stream>>>(x, dinv, xs);
    k_agg1<<<N_NODES / 8, 256, 0, stream>>>(row_start, csr, (const uint32*)xs, dinv, bufA);
    k_gemm8<IN_DIM, 1><<<N_NODES / 8, 256, 0, stream>>>(bufA, W1, b1, dinv, hs);

    // ----- layer 2: aggregate(hs) -> GEMM (f32 out) -----
    k_agg2<<<N_NODES / 8, 256, 0, stream>>>(row_start, csr, (const uint2*)hs, dinv, bufA);
    k_gemm8<HID, 0><<<N_NODES / 8, 256, 0, stream>>>(bufA, W2, b2, dinv, bufB);

    // ----- pool + head -----
    hipMemsetAsync(pooled, 0, (N_GRAPHS * HID + N_GRAPHS) * sizeof(float), stream);
    k_pool<<<(N_NODES + POOL_CHUNK - 1) / POOL_CHUNK, HID, 0, stream>>>(bufB, batch, pooled, cnt);
    k_head<<<1, 64, 0, stream>>>(pooled, cnt, Wfc, bfc, out);
}